// Round 1
// 363.681 us; speedup vs baseline: 1.0716x; 1.0716x over previous
//
#include <hip/hip_runtime.h>

#define E_TOTAL 32768
#define F_IN 17
#define HID 64
#define NJ 768

using bf16x8 = __attribute__((ext_vector_type(8))) short;
using f32x4  = __attribute__((ext_vector_type(4))) float;

__device__ __forceinline__ unsigned short f2bf(float x){
    unsigned u = __float_as_uint(x);
    u += 0x7fffu + ((u >> 16) & 1u);          // round-to-nearest-even
    return (unsigned short)(u >> 16);
}

// ---------------- Kernel 0: W3 (64x768 f32) -> W3T (768x64 bf16) ----------------
__global__ __launch_bounds__(256) void prep_w3(const float* __restrict__ W3,
                                               unsigned short* __restrict__ w3t){
    int t = blockIdx.x * 256 + threadIdx.x;   // 0..49151 ; t = n*64 + k
    int n = t >> 6, k = t & 63;
    w3t[t] = f2bf(W3[k * NJ + n]);
}

// ---------------- Kernel A: radial MLP, one wave per 4 edges ----------------
__global__ __launch_bounds__(256) void mlp_kernel(const float* __restrict__ feat,
        const float* __restrict__ W1, const float* __restrict__ b1, const float* __restrict__ g1,
        const float* __restrict__ W2, const float* __restrict__ b2, const float* __restrict__ g2,
        unsigned short* __restrict__ hb){
    __shared__ float sW1[F_IN * HID];
    __shared__ float sW2[HID * HID];
    __shared__ float sC[4 * HID];            // b1 | g1 | b2 | g2
    __shared__ float sFeat[16 * F_IN];
    __shared__ __align__(16) float sH1[16][HID];

    int tid = threadIdx.x;
    int e0  = blockIdx.x * 16;
    for (int i = tid; i < F_IN * HID; i += 256) sW1[i] = W1[i];
    for (int i = tid; i < HID * HID; i += 256) sW2[i] = W2[i];
    if (tid < 64) { sC[tid] = b1[tid]; sC[64 + tid] = g1[tid];
                    sC[128 + tid] = b2[tid]; sC[192 + tid] = g2[tid]; }
    for (int i = tid; i < 16 * F_IN; i += 256) sFeat[i] = feat[(size_t)e0 * F_IN + i];
    __syncthreads();

    int j = tid & 63, wv = tid >> 6;          // wave wv owns edges wv*4 .. wv*4+3
    float acc[4], x[4], s1[4], s2[4];

    // ---- layer 1: 17 -> 64 ----
    #pragma unroll
    for (int q = 0; q < 4; ++q) acc[q] = sC[j];
    for (int k = 0; k < F_IN; ++k){
        float w = sW1[k * 64 + j];
        #pragma unroll
        for (int q = 0; q < 4; ++q) acc[q] += sFeat[(wv * 4 + q) * F_IN + k] * w;
    }
    #pragma unroll
    for (int q = 0; q < 4; ++q){
        float a = acc[q];
        float sg = 1.0f / (1.0f + __expf(-a));
        x[q] = a * sg; s1[q] = x[q]; s2[q] = x[q] * x[q];
    }
    #pragma unroll
    for (int m = 1; m < 64; m <<= 1){
        #pragma unroll
        for (int q = 0; q < 4; ++q){
            s1[q] += __shfl_xor(s1[q], m);
            s2[q] += __shfl_xor(s2[q], m);
        }
    }
    #pragma unroll
    for (int q = 0; q < 4; ++q){
        float mu  = s1[q] * (1.0f / 64.0f);
        float var = s2[q] * (1.0f / 64.0f) - mu * mu;
        float rs  = rsqrtf(var + 1e-5f);
        sH1[wv * 4 + q][j] = (x[q] - mu) * rs * sC[64 + j];
    }
    // wave-local LDS write->read; LDS ops from one wave are ordered, no barrier needed

    // ---- layer 2: 64 -> 64 ----
    #pragma unroll
    for (int q = 0; q < 4; ++q) acc[q] = sC[128 + j];
    for (int k4 = 0; k4 < 16; ++k4){
        float hv[4][4];
        #pragma unroll
        for (int q = 0; q < 4; ++q) *(float4*)hv[q] = *(const float4*)&sH1[wv * 4 + q][k4 * 4];
        #pragma unroll
        for (int kk = 0; kk < 4; ++kk){
            float w = sW2[(k4 * 4 + kk) * 64 + j];
            #pragma unroll
            for (int q = 0; q < 4; ++q) acc[q] += hv[q][kk] * w;
        }
    }
    #pragma unroll
    for (int q = 0; q < 4; ++q){
        float a = acc[q];
        float sg = 1.0f / (1.0f + __expf(-a));
        x[q] = a * sg; s1[q] = x[q]; s2[q] = x[q] * x[q];
    }
    #pragma unroll
    for (int m = 1; m < 64; m <<= 1){
        #pragma unroll
        for (int q = 0; q < 4; ++q){
            s1[q] += __shfl_xor(s1[q], m);
            s2[q] += __shfl_xor(s2[q], m);
        }
    }
    #pragma unroll
    for (int q = 0; q < 4; ++q){
        float mu  = s1[q] * (1.0f / 64.0f);
        float var = s2[q] * (1.0f / 64.0f) - mu * mu;
        float rs  = rsqrtf(var + 1e-5f);
        float h2  = (x[q] - mu) * rs * sC[192 + j];
        hb[(size_t)(e0 + wv * 4 + q) * 64 + j] = f2bf(h2);
    }
}

// ---------------- Kernel B: R = h@W3 + b3 (MFMA) fused with einsum + write ----------------
// Chunked: 768 cols split into 4 slabs of 192. Per slab: GEMM (3 MFMA iters/wave)
// -> barrier -> einsum+store for the 4 'o' blocks this slab covers -> barrier.
// sR shrinks 49.6KB -> 12.4KB (stride 194: kg-groups 8 banks apart, conflict-free).
__global__ __launch_bounds__(256, 4) void tp_kernel(const unsigned short* __restrict__ hb,
        const unsigned short* __restrict__ w3t, const float* __restrict__ b3,
        const float* __restrict__ basis, float* __restrict__ out){
    __shared__ __align__(16) float sR[16 * 194];   // 16 edges x 192 slab cols (+2 pad)

    int tid = threadIdx.x;
    int e0  = blockIdx.x * 16;

    int wv = tid >> 6, l = tid & 63;
    int col = l & 15, kg = l >> 4;

    // A fragments: edge = col (16 rows shared by all waves), direct from global (L1/L2-hot)
    const unsigned short* hrow = hb + (size_t)(e0 + col) * 64;
    bf16x8 a0 = *(const bf16x8*)(hrow + kg * 8);        // k in [0,32)
    bf16x8 a1 = *(const bf16x8*)(hrow + 32 + kg * 8);   // k in [32,64)

    // einsum-side identity: lane = (group kg -> edge sub-index, col -> i)
    int e_loc = wv * 4 + kg;                 // edge this thread owns in phase 2
    int s     = col;                         // i index in phase 2
    float bs[27];
    const float* bp = basis + (size_t)(e0 + e_loc) * 27;
    #pragma unroll
    for (int z = 0; z < 27; ++z) bs[z] = bp[z];
    float* outE = out + (size_t)(e0 + e_loc) * 2304;
    const float* Rrow = sR + e_loc * 194;

    for (int c4 = 0; c4 < 4; ++c4){
        // ---- GEMM slab: wave wv covers slab cols [wv*48, wv*48+48) ----
        #pragma unroll
        for (int t = 0; t < 3; ++t){
            int n0 = c4 * 192 + wv * 48 + t * 16;         // global col base
            const unsigned short* wrow = w3t + (size_t)(n0 + col) * 64;
            bf16x8 bb0 = *(const bf16x8*)(wrow + kg * 8);
            bf16x8 bb1 = *(const bf16x8*)(wrow + 32 + kg * 8);
            f32x4 acc = {0.f, 0.f, 0.f, 0.f};
            acc = __builtin_amdgcn_mfma_f32_16x16x32_bf16(a0, bb0, acc, 0, 0, 0);
            acc = __builtin_amdgcn_mfma_f32_16x16x32_bf16(a1, bb1, acc, 0, 0, 0);
            float bj = b3[n0 + col];
            int cL = wv * 48 + t * 16 + col;              // slab-local col
            #pragma unroll
            for (int r = 0; r < 4; ++r){
                int e = kg * 4 + r;                       // D row = (lane>>4)*4 + reg
                sR[e * 194 + cL] = acc[r] + bj;
            }
        }
        __syncthreads();

        // ---- einsum slab: o = c4*4 .. c4*4+3 ----
        #pragma unroll
        for (int t2 = 0; t2 < 4; ++t2){
            int o = c4 * 4 + t2;
            const float* rp = Rrow + t2 * 48 + s * 3;
            float r0 = rp[0], r1 = rp[1], r2 = rp[2];
            #pragma unroll
            for (int d = 0; d < 3; ++d){
                float* p = outE + o * 144 + d * 48 + s * 3;
                int z = d * 9;
                p[0] = r0 * bs[z + 0] + r1 * bs[z + 1] + r2 * bs[z + 2];
                p[1] = r0 * bs[z + 3] + r1 * bs[z + 4] + r2 * bs[z + 5];
                p[2] = r0 * bs[z + 6] + r1 * bs[z + 7] + r2 * bs[z + 8];
            }
        }
        __syncthreads();   // protect sR before next slab overwrites it
    }
}

extern "C" void kernel_launch(void* const* d_in, const int* in_sizes, int n_in,
                              void* d_out, int out_size, void* d_ws, size_t ws_size,
                              hipStream_t stream) {
    const float* feat  = (const float*)d_in[0];
    const float* basis = (const float*)d_in[1];
    const float* W1 = (const float*)d_in[2];
    const float* b1 = (const float*)d_in[3];
    const float* g1 = (const float*)d_in[4];
    const float* W2 = (const float*)d_in[5];
    const float* b2 = (const float*)d_in[6];
    const float* g2 = (const float*)d_in[7];
    const float* W3 = (const float*)d_in[8];
    const float* b3 = (const float*)d_in[9];
    float* out = (float*)d_out;

    unsigned short* hbuf = (unsigned short*)d_ws;                       // 32768*64*2 = 4 MB
    unsigned short* w3t  = hbuf + (size_t)E_TOTAL * HID;                // 768*64*2 = 96 KB

    prep_w3<<<NJ * HID / 256, 256, 0, stream>>>(W3, w3t);
    mlp_kernel<<<E_TOTAL / 16, 256, 0, stream>>>(feat, W1, b1, g1, W2, b2, g2, hbuf);
    tp_kernel<<<E_TOTAL / 16, 256, 0, stream>>>(hbuf, w3t, b3, basis, out);
}

// Round 2
// 360.025 us; speedup vs baseline: 1.0825x; 1.0102x over previous
//
#include <hip/hip_runtime.h>

#define E_TOTAL 32768
#define F_IN 17
#define HID 64
#define NJ 768

using bf16x8 = __attribute__((ext_vector_type(8))) short;
using f32x4  = __attribute__((ext_vector_type(4))) float;

__device__ __forceinline__ unsigned short f2bf(float x){
    unsigned u = __float_as_uint(x);
    u += 0x7fffu + ((u >> 16) & 1u);          // round-to-nearest-even
    return (unsigned short)(u >> 16);
}

// ---------------- Kernel 0: W3 (64x768 f32) -> W3T (768x64 bf16) ----------------
__global__ __launch_bounds__(256) void prep_w3(const float* __restrict__ W3,
                                               unsigned short* __restrict__ w3t){
    int t = blockIdx.x * 256 + threadIdx.x;   // 0..49151 ; t = n*64 + k
    int n = t >> 6, k = t & 63;
    w3t[t] = f2bf(W3[k * NJ + n]);
}

// ---------------- Kernel A: radial MLP, one wave per 4 edges ----------------
__global__ __launch_bounds__(256) void mlp_kernel(const float* __restrict__ feat,
        const float* __restrict__ W1, const float* __restrict__ b1, const float* __restrict__ g1,
        const float* __restrict__ W2, const float* __restrict__ b2, const float* __restrict__ g2,
        unsigned short* __restrict__ hb){
    __shared__ float sW1[F_IN * HID];
    __shared__ float sW2[HID * HID];
    __shared__ float sC[4 * HID];            // b1 | g1 | b2 | g2
    __shared__ float sFeat[16 * F_IN];
    __shared__ __align__(16) float sH1[16][HID];

    int tid = threadIdx.x;
    int e0  = blockIdx.x * 16;
    for (int i = tid; i < F_IN * HID; i += 256) sW1[i] = W1[i];
    for (int i = tid; i < HID * HID; i += 256) sW2[i] = W2[i];
    if (tid < 64) { sC[tid] = b1[tid]; sC[64 + tid] = g1[tid];
                    sC[128 + tid] = b2[tid]; sC[192 + tid] = g2[tid]; }
    for (int i = tid; i < 16 * F_IN; i += 256) sFeat[i] = feat[(size_t)e0 * F_IN + i];
    __syncthreads();

    int j = tid & 63, wv = tid >> 6;          // wave wv owns edges wv*4 .. wv*4+3
    float acc[4], x[4], s1[4], s2[4];

    // ---- layer 1: 17 -> 64 ----
    #pragma unroll
    for (int q = 0; q < 4; ++q) acc[q] = sC[j];
    for (int k = 0; k < F_IN; ++k){
        float w = sW1[k * 64 + j];
        #pragma unroll
        for (int q = 0; q < 4; ++q) acc[q] += sFeat[(wv * 4 + q) * F_IN + k] * w;
    }
    #pragma unroll
    for (int q = 0; q < 4; ++q){
        float a = acc[q];
        float sg = 1.0f / (1.0f + __expf(-a));
        x[q] = a * sg; s1[q] = x[q]; s2[q] = x[q] * x[q];
    }
    #pragma unroll
    for (int m = 1; m < 64; m <<= 1){
        #pragma unroll
        for (int q = 0; q < 4; ++q){
            s1[q] += __shfl_xor(s1[q], m);
            s2[q] += __shfl_xor(s2[q], m);
        }
    }
    #pragma unroll
    for (int q = 0; q < 4; ++q){
        float mu  = s1[q] * (1.0f / 64.0f);
        float var = s2[q] * (1.0f / 64.0f) - mu * mu;
        float rs  = rsqrtf(var + 1e-5f);
        sH1[wv * 4 + q][j] = (x[q] - mu) * rs * sC[64 + j];
    }
    // wave-local LDS write->read; LDS ops from one wave are ordered, no barrier needed

    // ---- layer 2: 64 -> 64 ----
    #pragma unroll
    for (int q = 0; q < 4; ++q) acc[q] = sC[128 + j];
    for (int k4 = 0; k4 < 16; ++k4){
        float hv[4][4];
        #pragma unroll
        for (int q = 0; q < 4; ++q) *(float4*)hv[q] = *(const float4*)&sH1[wv * 4 + q][k4 * 4];
        #pragma unroll
        for (int kk = 0; kk < 4; ++kk){
            float w = sW2[(k4 * 4 + kk) * 64 + j];
            #pragma unroll
            for (int q = 0; q < 4; ++q) acc[q] += hv[q][kk] * w;
        }
    }
    #pragma unroll
    for (int q = 0; q < 4; ++q){
        float a = acc[q];
        float sg = 1.0f / (1.0f + __expf(-a));
        x[q] = a * sg; s1[q] = x[q]; s2[q] = x[q] * x[q];
    }
    #pragma unroll
    for (int m = 1; m < 64; m <<= 1){
        #pragma unroll
        for (int q = 0; q < 4; ++q){
            s1[q] += __shfl_xor(s1[q], m);
            s2[q] += __shfl_xor(s2[q], m);
        }
    }
    #pragma unroll
    for (int q = 0; q < 4; ++q){
        float mu  = s1[q] * (1.0f / 64.0f);
        float var = s2[q] * (1.0f / 64.0f) - mu * mu;
        float rs  = rsqrtf(var + 1e-5f);
        float h2  = (x[q] - mu) * rs * sC[192 + j];
        hb[(size_t)(e0 + wv * 4 + q) * 64 + j] = f2bf(h2);
    }
}

// ---------------- Kernel B: R = h@W3 + b3 (MFMA) fused with einsum + dense stores ----------------
// 4 slabs of 192 cols. Per slab: [copy prev sO -> global (dense f32x4)  ||  GEMM -> sR]
//   -> barrier -> einsum sR -> sO -> barrier.
// sO staging converts the stride-3 dword stores (12 lines/instr, ~1/3 write efficiency)
// into fully dense 1KB/wave float4 stores. LDS = 12.5K (sR) + 37.1K (sO) -> 3 blocks/CU.
__global__ __launch_bounds__(256, 3) void tp_kernel(const unsigned short* __restrict__ hb,
        const unsigned short* __restrict__ w3t, const float* __restrict__ b3,
        const float* __restrict__ basis, float* __restrict__ out){
    __shared__ __align__(16) float sR[16 * 196];   // 16 edges x 192 slab cols (+4 pad, 16B-mult)
    __shared__ __align__(16) float sO[16 * 580];   // 16 edges x 576 slab outputs (+4 pad)

    int tid = threadIdx.x;
    int e0  = blockIdx.x * 16;

    int wv = tid >> 6, l = tid & 63;
    int col = l & 15, kg = l >> 4;

    // A fragments: edge = col (16 rows shared by all waves), direct from global (L2-hot)
    const unsigned short* hrow = hb + (size_t)(e0 + col) * 64;
    bf16x8 a0 = *(const bf16x8*)(hrow + kg * 8);        // k in [0,32)
    bf16x8 a1 = *(const bf16x8*)(hrow + 32 + kg * 8);   // k in [32,64)

    // einsum-side identity: kg -> edge sub-index, col -> i
    int e_loc = wv * 4 + kg;
    int s     = col;
    float bs[27];
    const float* bp = basis + (size_t)(e0 + e_loc) * 27;
    #pragma unroll
    for (int z = 0; z < 27; ++z) bs[z] = bp[z];

    float* outB = out + (size_t)e0 * 2304;
    const float* Rrow = sR + e_loc * 196;
    float* Orow = sO + e_loc * 580;

    for (int c4 = 0; c4 < 4; ++c4){
        // ---- phase A: copy slab c4-1 (dense float4) || GEMM slab c4 ----
        if (c4 > 0){
            #pragma unroll
            for (int k = 0; k < 9; ++k){
                int idx4 = k * 256 + tid;          // 0..2303 float4s this slab
                int e = idx4 / 144, c = idx4 - e * 144;
                f32x4 v = *(const f32x4*)(sO + e * 580 + c * 4);
                *(f32x4*)(outB + (size_t)e * 2304 + (c4 - 1) * 576 + c * 4) = v;
            }
        }
        #pragma unroll
        for (int t = 0; t < 3; ++t){
            int n0 = c4 * 192 + wv * 48 + t * 16;         // global col base
            const unsigned short* wrow = w3t + (size_t)(n0 + col) * 64;
            bf16x8 bb0 = *(const bf16x8*)(wrow + kg * 8);
            bf16x8 bb1 = *(const bf16x8*)(wrow + 32 + kg * 8);
            f32x4 acc = {0.f, 0.f, 0.f, 0.f};
            acc = __builtin_amdgcn_mfma_f32_16x16x32_bf16(a0, bb0, acc, 0, 0, 0);
            acc = __builtin_amdgcn_mfma_f32_16x16x32_bf16(a1, bb1, acc, 0, 0, 0);
            float bj = b3[n0 + col];
            int cL = wv * 48 + t * 16 + col;              // slab-local col
            #pragma unroll
            for (int r = 0; r < 4; ++r)
                sR[(kg * 4 + r) * 196 + cL] = acc[r] + bj;   // D row = (lane>>4)*4 + reg
        }
        __syncthreads();

        // ---- phase B: einsum sR -> sO (o = c4*4 .. c4*4+3) ----
        #pragma unroll
        for (int t2 = 0; t2 < 4; ++t2){
            const float* rp = Rrow + t2 * 48 + s * 3;
            float r0 = rp[0], r1 = rp[1], r2 = rp[2];
            #pragma unroll
            for (int d = 0; d < 3; ++d){
                float* p = Orow + t2 * 144 + d * 48 + s * 3;
                int z = d * 9;
                p[0] = r0 * bs[z + 0] + r1 * bs[z + 1] + r2 * bs[z + 2];
                p[1] = r0 * bs[z + 3] + r1 * bs[z + 4] + r2 * bs[z + 5];
                p[2] = r0 * bs[z + 6] + r1 * bs[z + 7] + r2 * bs[z + 8];
            }
        }
        __syncthreads();
    }

    // ---- epilogue: copy slab 3 ----
    #pragma unroll
    for (int k = 0; k < 9; ++k){
        int idx4 = k * 256 + tid;
        int e = idx4 / 144, c = idx4 - e * 144;
        f32x4 v = *(const f32x4*)(sO + e * 580 + c * 4);
        *(f32x4*)(outB + (size_t)e * 2304 + 3 * 576 + c * 4) = v;
    }
}

extern "C" void kernel_launch(void* const* d_in, const int* in_sizes, int n_in,
                              void* d_out, int out_size, void* d_ws, size_t ws_size,
                              hipStream_t stream) {
    const float* feat  = (const float*)d_in[0];
    const float* basis = (const float*)d_in[1];
    const float* W1 = (const float*)d_in[2];
    const float* b1 = (const float*)d_in[3];
    const float* g1 = (const float*)d_in[4];
    const float* W2 = (const float*)d_in[5];
    const float* b2 = (const float*)d_in[6];
    const float* g2 = (const float*)d_in[7];
    const float* W3 = (const float*)d_in[8];
    const float* b3 = (const float*)d_in[9];
    float* out = (float*)d_out;

    unsigned short* hbuf = (unsigned short*)d_ws;                       // 32768*64*2 = 4 MB
    unsigned short* w3t  = hbuf + (size_t)E_TOTAL * HID;                // 768*64*2 = 96 KB

    prep_w3<<<NJ * HID / 256, 256, 0, stream>>>(W3, w3t);
    mlp_kernel<<<E_TOTAL / 16, 256, 0, stream>>>(feat, W1, b1, g1, W2, b2, g2, hbuf);
    tp_kernel<<<E_TOTAL / 16, 256, 0, stream>>>(hbuf, w3t, b3, basis, out);
}

// Round 3
// 348.913 us; speedup vs baseline: 1.1170x; 1.0318x over previous
//
#include <hip/hip_runtime.h>

#define E_TOTAL 32768
#define F_IN 17
#define HID 64
#define NJ 768

using bf16x8 = __attribute__((ext_vector_type(8))) short;
using f32x4  = __attribute__((ext_vector_type(4))) float;

__device__ __forceinline__ unsigned short f2bf(float x){
    unsigned u = __float_as_uint(x);
    u += 0x7fffu + ((u >> 16) & 1u);          // round-to-nearest-even
    return (unsigned short)(u >> 16);
}

// Canonical GCN wave64 sum: row_shr 1/2/4/8 + row_bcast15(rows1,3) + row_bcast31(rows2,3),
// then readlane 63 -> uniform SGPR broadcast. VALU pipe only (no LDS traffic).
__device__ __forceinline__ float wave_sum(float x){
    x += __int_as_float(__builtin_amdgcn_update_dpp(0, __float_as_int(x), 0x111, 0xf, 0xf, true));
    x += __int_as_float(__builtin_amdgcn_update_dpp(0, __float_as_int(x), 0x112, 0xf, 0xf, true));
    x += __int_as_float(__builtin_amdgcn_update_dpp(0, __float_as_int(x), 0x114, 0xf, 0xf, true));
    x += __int_as_float(__builtin_amdgcn_update_dpp(0, __float_as_int(x), 0x118, 0xf, 0xf, true));
    x += __int_as_float(__builtin_amdgcn_update_dpp(0, __float_as_int(x), 0x142, 0xa, 0xf, true));
    x += __int_as_float(__builtin_amdgcn_update_dpp(0, __float_as_int(x), 0x143, 0xc, 0xf, true));
    return __int_as_float(__builtin_amdgcn_readlane(__float_as_int(x), 63));
}

// ---------------- Kernel 0: W3 (64x768 f32) -> W3T (768x64 bf16) ----------------
__global__ __launch_bounds__(256) void prep_w3(const float* __restrict__ W3,
                                               unsigned short* __restrict__ w3t){
    int t = blockIdx.x * 256 + threadIdx.x;   // 0..49151 ; t = n*64 + k
    int n = t >> 6, k = t & 63;
    w3t[t] = f2bf(W3[k * NJ + n]);
}

// ---------------- Fused kernel: radial MLP + (h@W3+b3) MFMA + einsum + dense stores ----
// LDS union: [persistent sH 2304B][ region: MLP(26.9K) aliased with TP(sR 12.5K + sO 37.1K) ]
// = 51,968 B -> 3 blocks/CU. Aliasing is barrier-protected (MLP reads all precede first
// sR/sO write). Fusion overlaps MLP VALU work of some blocks with store drain of others.
__global__ __launch_bounds__(256, 3) void fused_kernel(const float* __restrict__ feat,
        const float* __restrict__ W1, const float* __restrict__ b1, const float* __restrict__ g1,
        const float* __restrict__ W2, const float* __restrict__ b2, const float* __restrict__ g2,
        const unsigned short* __restrict__ w3t, const float* __restrict__ b3,
        const float* __restrict__ basis, float* __restrict__ out){
    __shared__ __align__(16) char smem[51968];
    unsigned short* sH  = (unsigned short*)smem;       // 16 x 72 shorts (bf16 h2, padded)
    char* rgn = smem + 2304;
    float* sW1 = (float*)rgn;                          // 4352 B  (17x64)
    float* sW2 = (float*)(rgn + 4352);                 // 16384 B (64x64)
    float* sC  = (float*)(rgn + 20736);                // 1024 B  (b1|g1|b2|g2)
    float* sFe = (float*)(rgn + 21760);                // 1088 B  (16x17)
    float* sH1 = (float*)(rgn + 22848);                // 4096 B  (16x64)
    float* sR  = (float*)rgn;                          // 12544 B (16x196)   [aliases W1+W2lo]
    float* sO  = (float*)(rgn + 12544);                // 37120 B (16x580)   [aliases W2hi..H1]

    int tid = threadIdx.x;
    int e0  = blockIdx.x * 16;
    int wv = tid >> 6, l = tid & 63;
    int j = l;                                 // MLP channel
    int col = l & 15, kg = l >> 4;             // MFMA lane split
    int e_loc = wv * 4 + kg;                   // einsum edge, phase-2 identity
    int s = col;                               // einsum i index

    // ---- vectorized staging (float4) ----
    for (int i = tid; i < 272; i += 256) ((f32x4*)sW1)[i] = ((const f32x4*)W1)[i];
    #pragma unroll
    for (int k = 0; k < 4; ++k) ((f32x4*)sW2)[k * 256 + tid] = ((const f32x4*)W2)[k * 256 + tid];
    if (tid < 64){
        int g = tid >> 4, r = tid & 15;
        const float* src = (g == 0) ? b1 : (g == 1) ? g1 : (g == 2) ? b2 : g2;
        ((f32x4*)sC)[tid] = ((const f32x4*)src)[r];
    }
    if (tid < 68) ((f32x4*)sFe)[tid] = ((const f32x4*)(feat + (size_t)e0 * F_IN))[tid];
    __syncthreads();

    float acc[4], x[4];

    // ---- layer 1: 17 -> 64 ----
    #pragma unroll
    for (int q = 0; q < 4; ++q) acc[q] = sC[j];
    for (int k = 0; k < F_IN; ++k){
        float w = sW1[k * 64 + j];
        #pragma unroll
        for (int q = 0; q < 4; ++q) acc[q] += sFe[(wv * 4 + q) * F_IN + k] * w;
    }
    #pragma unroll
    for (int q = 0; q < 4; ++q){
        float a = acc[q];
        float sg = 1.0f / (1.0f + __expf(-a));
        x[q] = a * sg;
        float s1 = wave_sum(x[q]);
        float s2 = wave_sum(x[q] * x[q]);
        float mu  = s1 * (1.0f / 64.0f);
        float var = s2 * (1.0f / 64.0f) - mu * mu;
        float rs  = rsqrtf(var + 1e-5f);
        sH1[(wv * 4 + q) * 64 + j] = (x[q] - mu) * rs * sC[64 + j];
    }
    // wave-local LDS write->read: one wave's LDS ops are ordered, no barrier needed

    // ---- layer 2: 64 -> 64 ----
    #pragma unroll
    for (int q = 0; q < 4; ++q) acc[q] = sC[128 + j];
    for (int k4 = 0; k4 < 16; ++k4){
        float hv[4][4];
        #pragma unroll
        for (int q = 0; q < 4; ++q) *(float4*)hv[q] = *(const float4*)&sH1[(wv * 4 + q) * 64 + k4 * 4];
        #pragma unroll
        for (int kk = 0; kk < 4; ++kk){
            float w = sW2[(k4 * 4 + kk) * 64 + j];
            #pragma unroll
            for (int q = 0; q < 4; ++q) acc[q] += hv[q][kk] * w;
        }
    }
    #pragma unroll
    for (int q = 0; q < 4; ++q){
        float a = acc[q];
        float sg = 1.0f / (1.0f + __expf(-a));
        x[q] = a * sg;
        float s1 = wave_sum(x[q]);
        float s2 = wave_sum(x[q] * x[q]);
        float mu  = s1 * (1.0f / 64.0f);
        float var = s2 * (1.0f / 64.0f) - mu * mu;
        float rs  = rsqrtf(var + 1e-5f);
        sH[(wv * 4 + q) * 72 + j] = f2bf((x[q] - mu) * rs * sC[192 + j]);
    }

    // basis for this thread's einsum edge (prefetch under the barrier)
    float bs[27];
    {
        const float* bp = basis + (size_t)(e0 + e_loc) * 27;
        #pragma unroll
        for (int z = 0; z < 27; ++z) bs[z] = bp[z];
    }
    __syncthreads();   // all sH written; all MLP reads of region-A done (aliasing fence)

    // ---- A fragments from sH (stride 72 shorts -> conflict-free b128 reads) ----
    bf16x8 a0 = *(const bf16x8*)(sH + col * 72 + kg * 8);        // k in [0,32)
    bf16x8 a1 = *(const bf16x8*)(sH + col * 72 + 32 + kg * 8);   // k in [32,64)

    float* outB = out + (size_t)e0 * 2304;
    const float* Rrow = sR + e_loc * 196;
    float* Orow = sO + e_loc * 580;

    for (int c4 = 0; c4 < 4; ++c4){
        // ---- phase A: copy slab c4-1 (dense float4) || GEMM slab c4 -> sR ----
        if (c4 > 0){
            #pragma unroll
            for (int k = 0; k < 9; ++k){
                int idx4 = k * 256 + tid;          // 0..2303 float4s this slab
                int e = idx4 / 144, c = idx4 - e * 144;
                f32x4 v = *(const f32x4*)(sO + e * 580 + c * 4);
                *(f32x4*)(outB + (size_t)e * 2304 + (c4 - 1) * 576 + c * 4) = v;
            }
        }
        #pragma unroll
        for (int t = 0; t < 3; ++t){
            int n0 = c4 * 192 + wv * 48 + t * 16;         // global col base
            const unsigned short* wrow = w3t + (size_t)(n0 + col) * 64;
            bf16x8 bb0 = *(const bf16x8*)(wrow + kg * 8);
            bf16x8 bb1 = *(const bf16x8*)(wrow + 32 + kg * 8);
            f32x4 acc2 = {0.f, 0.f, 0.f, 0.f};
            acc2 = __builtin_amdgcn_mfma_f32_16x16x32_bf16(a0, bb0, acc2, 0, 0, 0);
            acc2 = __builtin_amdgcn_mfma_f32_16x16x32_bf16(a1, bb1, acc2, 0, 0, 0);
            float bj = b3[n0 + col];
            int cL = wv * 48 + t * 16 + col;              // slab-local col
            #pragma unroll
            for (int r = 0; r < 4; ++r)
                sR[(kg * 4 + r) * 196 + cL] = acc2[r] + bj;   // D row = (lane>>4)*4 + reg
        }
        __syncthreads();

        // ---- phase B: einsum sR -> sO (o = c4*4 .. c4*4+3) ----
        #pragma unroll
        for (int t2 = 0; t2 < 4; ++t2){
            const float* rp = Rrow + t2 * 48 + s * 3;
            float r0 = rp[0], r1 = rp[1], r2 = rp[2];
            #pragma unroll
            for (int d = 0; d < 3; ++d){
                float* p = Orow + t2 * 144 + d * 48 + s * 3;
                int z = d * 9;
                p[0] = r0 * bs[z + 0] + r1 * bs[z + 1] + r2 * bs[z + 2];
                p[1] = r0 * bs[z + 3] + r1 * bs[z + 4] + r2 * bs[z + 5];
                p[2] = r0 * bs[z + 6] + r1 * bs[z + 7] + r2 * bs[z + 8];
            }
        }
        __syncthreads();
    }

    // ---- epilogue: copy slab 3 ----
    #pragma unroll
    for (int k = 0; k < 9; ++k){
        int idx4 = k * 256 + tid;
        int e = idx4 / 144, c = idx4 - e * 144;
        f32x4 v = *(const f32x4*)(sO + e * 580 + c * 4);
        *(f32x4*)(outB + (size_t)e * 2304 + 3 * 576 + c * 4) = v;
    }
}

extern "C" void kernel_launch(void* const* d_in, const int* in_sizes, int n_in,
                              void* d_out, int out_size, void* d_ws, size_t ws_size,
                              hipStream_t stream) {
    const float* feat  = (const float*)d_in[0];
    const float* basis = (const float*)d_in[1];
    const float* W1 = (const float*)d_in[2];
    const float* b1 = (const float*)d_in[3];
    const float* g1 = (const float*)d_in[4];
    const float* W2 = (const float*)d_in[5];
    const float* b2 = (const float*)d_in[6];
    const float* g2 = (const float*)d_in[7];
    const float* W3 = (const float*)d_in[8];
    const float* b3 = (const float*)d_in[9];
    float* out = (float*)d_out;

    unsigned short* w3t = (unsigned short*)d_ws;        // 768*64*2 = 96 KB

    prep_w3<<<NJ * HID / 256, 256, 0, stream>>>(W3, w3t);
    fused_kernel<<<E_TOTAL / 16, 256, 0, stream>>>(feat, W1, b1, g1, W2, b2, g2,
                                                   w3t, b3, basis, out);
}